// Round 5
// baseline (222.358 us; speedup 1.0000x reference)
//
#include <hip/hip_runtime.h>
#include <stdint.h>

#define SS 4096
#define EE 256
// log2(e)/16  (logit scale 1/NORM_FACTOR folded into exp2 conversion)
#define C2 0.0901684400555602f

typedef __bf16 bf16x8 __attribute__((ext_vector_type(8)));
typedef float  f32x4  __attribute__((ext_vector_type(4)));
typedef float  f32x16 __attribute__((ext_vector_type(16)));

#if __has_builtin(__builtin_amdgcn_exp2f)
#define EXP2(x) __builtin_amdgcn_exp2f(x)
#else
#define EXP2(x) exp2f(x)
#endif
#if __has_builtin(__builtin_amdgcn_rcpf)
#define RCP(x) __builtin_amdgcn_rcpf(x)
#else
#define RCP(x) (1.0f / (x))
#endif

__device__ __forceinline__ uint16_t bf16_rn(float f) {
  uint32_t u = __float_as_uint(f);
  uint32_t r = (u + 0x7fffu + ((u >> 16) & 1u)) >> 16;
  return (uint16_t)r;
}
__device__ __forceinline__ float bf2f(uint16_t h) {
  return __uint_as_float(((uint32_t)h) << 16);
}
__device__ __forceinline__ bf16x8 pack_bf8(float4 a, float4 b) {
  union { bf16x8 v; uint16_t u[8]; } r;
  r.u[0] = bf16_rn(a.x); r.u[1] = bf16_rn(a.y);
  r.u[2] = bf16_rn(a.z); r.u[3] = bf16_rn(a.w);
  r.u[4] = bf16_rn(b.x); r.u[5] = bf16_rn(b.y);
  r.u[6] = bf16_rn(b.z); r.u[7] = bf16_rn(b.w);
  return r.v;
}

__device__ __forceinline__ f32x4 mfma16(bf16x8 a, bf16x8 b, f32x4 c) {
  return __builtin_amdgcn_mfma_f32_16x16x32_bf16(a, b, c, 0, 0, 0);
}
__device__ __forceinline__ f32x16 mfma32(bf16x8 a, bf16x8 b, f32x16 c) {
  return __builtin_amdgcn_mfma_f32_32x32x16_bf16(a, b, c, 0, 0, 0);
}

// Stage R rows x 512B global -> LDS via global_load_lds(16B), 5-bit XOR
// swizzle: logical chunk cc of row r lands at physical chunk cc^(r&31).
// (5-bit, not 3-bit: the 32x32 MFMA B-read has 32 lanes sharing one cc,
// so the full row index must spread the chunk index.) Paired with read_frag.
// Register-free transport (R2 lesson: global->reg streaming starves VGPRs).
template<int R>
__device__ __forceinline__ void stage_tile(const uint16_t* gsrc, char* lds, int tid) {
  constexpr int NPER = (R * 32) / 256;
  const int wave = tid >> 6;
  #pragma unroll
  for (int c = 0; c < NPER; ++c) {
    int chunk = c * 256 + tid;
    int r = chunk >> 5;
    int ccl = (chunk & 31) ^ (r & 31);
    const char* gp = (const char*)gsrc + (r * 32 + ccl) * 16;
    char* lp = lds + (c * 256 + wave * 64) * 16;
    __builtin_amdgcn_global_load_lds(
        (const __attribute__((address_space(1))) uint32_t*)(uintptr_t)gp,
        (__attribute__((address_space(3))) uint32_t*)(uintptr_t)lp,
        16, 0, 0);
  }
}

__device__ __forceinline__ bf16x8 read_frag(const char* lds, int row, int cc) {
  int ccp = cc ^ (row & 31);
  return *(const bf16x8*)(lds + (row * 32 + ccp) * 16);
}

// ---------------- K0: W transpose-cast -> WT[out][in] bf16 ----------------
__global__ void wcast_kernel(const float* __restrict__ Wq, const float* __restrict__ Wk,
                             const float* __restrict__ Wv, uint16_t* __restrict__ wt) {
  __shared__ float t[64][65];
  const int tb = blockIdx.x, tid = threadIdx.x;
  const int mat = tb >> 4, tt = tb & 15;
  const int ib = (tt >> 2) * 64, ob = (tt & 3) * 64;
  const float* W = (mat == 0) ? Wq : (mat == 1) ? Wk : Wv;
  #pragma unroll
  for (int p = 0; p < 4; ++p) {
    int idx = p * 256 + tid;
    int r = idx >> 4, c4 = idx & 15;
    float4 f = *(const float4*)&W[(size_t)(ib + r) * 256 + ob + c4 * 4];
    t[r][c4 * 4 + 0] = f.x; t[r][c4 * 4 + 1] = f.y;
    t[r][c4 * 4 + 2] = f.z; t[r][c4 * 4 + 3] = f.w;
  }
  __syncthreads();
  #pragma unroll
  for (int p = 0; p < 4; ++p) {
    int idx = p * 256 + tid;
    int o = idx >> 4, i4 = idx & 15;
    ushort4 u;
    u.x = bf16_rn(t[i4 * 4 + 0][o]);
    u.y = bf16_rn(t[i4 * 4 + 1][o]);
    u.z = bf16_rn(t[i4 * 4 + 2][o]);
    u.w = bf16_rn(t[i4 * 4 + 3][o]);
    *(ushort4*)&wt[((size_t)mat * 256 + ob + o) * 256 + ib + i4 * 4] = u;
  }
}

// ---------------- K1: fused QKV projection GEMM ----------------
__global__ __launch_bounds__(256, 2) void qkv_kernel(
    const float* __restrict__ x, const uint16_t* __restrict__ wt,
    const float* __restrict__ bq, const float* __restrict__ bk, const float* __restrict__ bv,
    uint16_t* __restrict__ qo, uint16_t* __restrict__ ko, uint16_t* __restrict__ vo) {
  __shared__ char wsm[2][32768];
  const int tid = threadIdx.x;
  const int lane = tid & 63, wave = tid >> 6, quad = lane >> 4, lr = lane & 15;
  const int m0 = (blockIdx.x >> 2) * 256;
  const int cchunk = blockIdx.x & 3;          // 4 chunks of 192 cols over [q|k|v]
  stage_tile<64>(wt + (size_t)(cchunk * 192) * 256, wsm[0], tid);
  const float* ab = x + (size_t)(m0 + wave * 64) * EE;
  bf16x8 a[4][8];
  #pragma unroll
  for (int ms = 0; ms < 4; ++ms)
    #pragma unroll
    for (int f = 0; f < 8; ++f) {
      const float* rp = ab + (size_t)(ms * 16 + lr) * EE + f * 32 + quad * 8;
      a[ms][f] = pack_bf8(*(const float4*)rp, *(const float4*)(rp + 4));
    }
  for (int nc = 0; nc < 3; ++nc) {
    __syncthreads();
    if (nc < 2)
      stage_tile<64>(wt + (size_t)(cchunk * 192 + (nc + 1) * 64) * 256, wsm[(nc + 1) & 1], tid);
    const char* tile = wsm[nc & 1];
    #pragma unroll
    for (int nt = 0; nt < 4; ++nt) {
      const int eg0 = cchunk * 192 + nc * 64 + nt * 16;
      const int mat = eg0 >> 8;
      const int e = (eg0 & 255) + lr;
      const float* bias = (mat == 0) ? bq : (mat == 1) ? bk : bv;
      uint16_t* outp = (mat == 0) ? qo : (mat == 1) ? ko : vo;
      bf16x8 bf[8];
      #pragma unroll
      for (int f = 0; f < 8; ++f) bf[f] = read_frag(tile, nt * 16 + lr, f * 4 + quad);
      f32x4 acc[4] = {};
      #pragma unroll
      for (int f = 0; f < 8; ++f)
        #pragma unroll
        for (int ms = 0; ms < 4; ++ms)
          acc[ms] = mfma16(a[ms][f], bf[f], acc[ms]);
      const float bsv = bias[e];
      #pragma unroll
      for (int ms = 0; ms < 4; ++ms)
        #pragma unroll
        for (int r = 0; r < 4; ++r) {
          int row = m0 + wave * 64 + ms * 16 + quad * 4 + r;
          outp[(size_t)row * EE + e] = bf16_rn(acc[ms][r] + bsv);
        }
    }
  }
}

// ---------------- K2: pass A  l[s] = sum_t exp(q_s.k_t/16) ----------------
// 32x32x16 MFMA (2495 TF rate vs 2075 for 16x16x32; half the instructions).
// A (64 q-rows/wave = 2 row-tiles) resident; K via 64-key dbuf LDS, 8 iters.
// A layout: row = lane&31, k = (lane>>5)*8 + j.  C/D: col = lane&31,
// row = (reg&3) + 8*(reg>>2) + 4*(lane>>5)   [m74/m101 verified].
__global__ __launch_bounds__(256, 2) void scores_l_kernel(
    const uint16_t* __restrict__ q, const uint16_t* __restrict__ k,
    float* __restrict__ lacc) {
  __shared__ char kt[2][32768];
  const int tid = threadIdx.x;
  const int lane = tid & 63, wave = tid >> 6;
  const int col5 = lane & 31, half = lane >> 5;
  const int idx = blockIdx.x;
  const int b = idx >> 7, rem = idx & 127, qblk = rem >> 3, kch = rem & 7;
  const uint16_t* qb = q + (size_t)(b * SS + qblk * 256 + wave * 64) * EE;
  const uint16_t* kb = k + (size_t)(b * SS + kch * 512) * EE;
  stage_tile<64>(kb, kt[0], tid);
  bf16x8 a[2][16];
  #pragma unroll
  for (int rt = 0; rt < 2; ++rt)
    #pragma unroll
    for (int f = 0; f < 16; ++f)
      a[rt][f] = *(const bf16x8*)(qb + (size_t)(rt * 32 + col5) * EE + f * 16 + half * 8);
  float accl[32];
  #pragma unroll
  for (int i = 0; i < 32; ++i) accl[i] = 0.f;
  for (int it = 0; it < 8; ++it) {
    __syncthreads();                      // stage(it) landed; buf (it-1) free
    if (it + 1 < 8) stage_tile<64>(kb + (size_t)(it + 1) * 64 * EE, kt[(it + 1) & 1], tid);
    const char* tile = kt[it & 1];
    #pragma unroll
    for (int kt2 = 0; kt2 < 2; ++kt2) {
      f32x16 acc0 = {}, acc1 = {};
      #pragma unroll
      for (int f = 0; f < 16; ++f) {
        bf16x8 bf = read_frag(tile, kt2 * 32 + col5, f * 2 + half);
        acc0 = mfma32(a[0][f], bf, acc0);
        acc1 = mfma32(a[1][f], bf, acc1);
      }
      #pragma unroll
      for (int reg = 0; reg < 16; ++reg) {
        accl[reg]      += EXP2(acc0[reg] * C2);
        accl[16 + reg] += EXP2(acc1[reg] * C2);
      }
    }
  }
  // reduce over cols (32 lanes within each half; halves hold disjoint rows)
  #pragma unroll
  for (int d = 1; d < 32; d <<= 1)
    #pragma unroll
    for (int i = 0; i < 32; ++i)
      accl[i] += __shfl_xor(accl[i], d, 64);
  if (col5 == 0) {
    float* lp = lacc + b * SS + qblk * 256 + wave * 64;
    #pragma unroll
    for (int rt = 0; rt < 2; ++rt)
      #pragma unroll
      for (int reg = 0; reg < 16; ++reg) {
        int row = rt * 32 + (reg & 3) + 8 * (reg >> 2) + 4 * half;
        atomicAdd(&lp[row], accl[rt * 16 + reg]);
      }
  }
}

// ---------------- K3: pass B  w[t] = sum_s exp(q_s.k_t/16) / l[s] ----------
// Mirror: A = 64 k-rows/wave, tile = queries; rlv (1/l per col s) folded in.
__global__ __launch_bounds__(256, 2) void scores_w_kernel(
    const uint16_t* __restrict__ q, const uint16_t* __restrict__ k,
    const float* __restrict__ lacc, float* __restrict__ wacc) {
  __shared__ char qt[2][32768];
  const int tid = threadIdx.x;
  const int lane = tid & 63, wave = tid >> 6;
  const int col5 = lane & 31, half = lane >> 5;
  const int idx = blockIdx.x;
  const int b = idx >> 7, rem = idx & 127, kblk = rem >> 3, sch = rem & 7;
  const uint16_t* kb = k + (size_t)(b * SS + kblk * 256 + wave * 64) * EE;
  const uint16_t* qb = q + (size_t)(b * SS + sch * 512) * EE;
  const float* rlb = lacc + b * SS + sch * 512;
  stage_tile<64>(qb, qt[0], tid);
  bf16x8 a[2][16];
  #pragma unroll
  for (int rt = 0; rt < 2; ++rt)
    #pragma unroll
    for (int f = 0; f < 16; ++f)
      a[rt][f] = *(const bf16x8*)(kb + (size_t)(rt * 32 + col5) * EE + f * 16 + half * 8);
  float accw[32];
  #pragma unroll
  for (int i = 0; i < 32; ++i) accw[i] = 0.f;
  for (int it = 0; it < 8; ++it) {
    __syncthreads();
    if (it + 1 < 8) stage_tile<64>(qb + (size_t)(it + 1) * 64 * EE, qt[(it + 1) & 1], tid);
    const char* tile = qt[it & 1];
    #pragma unroll
    for (int kt2 = 0; kt2 < 2; ++kt2) {
      float rlv = RCP(rlb[it * 64 + kt2 * 32 + col5]);   // 1/l for this col s
      f32x16 acc0 = {}, acc1 = {};
      #pragma unroll
      for (int f = 0; f < 16; ++f) {
        bf16x8 bf = read_frag(tile, kt2 * 32 + col5, f * 2 + half);
        acc0 = mfma32(a[0][f], bf, acc0);
        acc1 = mfma32(a[1][f], bf, acc1);
      }
      #pragma unroll
      for (int reg = 0; reg < 16; ++reg) {
        accw[reg]      += EXP2(acc0[reg] * C2) * rlv;
        accw[16 + reg] += EXP2(acc1[reg] * C2) * rlv;
      }
    }
  }
  #pragma unroll
  for (int d = 1; d < 32; d <<= 1)
    #pragma unroll
    for (int i = 0; i < 32; ++i)
      accw[i] += __shfl_xor(accw[i], d, 64);
  if (col5 == 0) {
    float* wp = wacc + b * SS + kblk * 256 + wave * 64;
    #pragma unroll
    for (int rt = 0; rt < 2; ++rt)
      #pragma unroll
      for (int reg = 0; reg < 16; ++reg) {
        int row = rt * 32 + (reg & 3) + 8 * (reg >> 2) + 4 * half;
        atomicAdd(&wp[row], accw[rt * 16 + reg]);
      }
  }
}

// ---------------- K4a: pool stage 1 — per-64-row partial sums ----------------
__global__ void pool1_kernel(const float* __restrict__ wsum, const uint16_t* __restrict__ v,
                             float* __restrict__ partial) {
  __shared__ float red[4][256];
  const int b = blockIdx.x >> 6, tc = blockIdx.x & 63;
  const int tq = threadIdx.x >> 6, eg = threadIdx.x & 63;
  float acc[4] = {0.f, 0.f, 0.f, 0.f};
  const float* wp = wsum + b * SS + tc * 64;
  const uint16_t* vp = v + (size_t)(b * SS + tc * 64) * EE + eg * 4;
  #pragma unroll 4
  for (int t = tq; t < 64; t += 4) {
    float wv = wp[t];
    ushort4 x4 = *(const ushort4*)(vp + (size_t)t * EE);
    acc[0] += wv * bf2f(x4.x);
    acc[1] += wv * bf2f(x4.y);
    acc[2] += wv * bf2f(x4.z);
    acc[3] += wv * bf2f(x4.w);
  }
  #pragma unroll
  for (int j = 0; j < 4; ++j) red[tq][eg * 4 + j] = acc[j];
  __syncthreads();
  if (tq == 0) {
    float4 s;
    s.x = red[0][eg * 4 + 0] + red[1][eg * 4 + 0] + red[2][eg * 4 + 0] + red[3][eg * 4 + 0];
    s.y = red[0][eg * 4 + 1] + red[1][eg * 4 + 1] + red[2][eg * 4 + 1] + red[3][eg * 4 + 1];
    s.z = red[0][eg * 4 + 2] + red[1][eg * 4 + 2] + red[2][eg * 4 + 2] + red[3][eg * 4 + 2];
    s.w = red[0][eg * 4 + 3] + red[1][eg * 4 + 3] + red[2][eg * 4 + 3] + red[3][eg * 4 + 3];
    *(float4*)&partial[(size_t)blockIdx.x * 256 + eg * 4] = s;
  }
}

// ---------------- K4b: pool stage 2 — reduce 64 partials, write out ---------
__global__ void pool2_kernel(const float* __restrict__ partial, float* __restrict__ out) {
  const int b = blockIdx.x, e = threadIdx.x;
  float s = 0.f;
  #pragma unroll 8
  for (int c = 0; c < 64; ++c)
    s += partial[(size_t)(b * 64 + c) * 256 + e];
  out[b * 256 + e] = s * (1.0f / 4096.0f);
}

// ---------------- launch ----------------
extern "C" void kernel_launch(void* const* d_in, const int* in_sizes, int n_in,
                              void* d_out, int out_size, void* d_ws, size_t ws_size,
                              hipStream_t stream) {
  const float* x  = (const float*)d_in[0];
  const float* Wq = (const float*)d_in[1];
  const float* bq = (const float*)d_in[2];
  const float* Wk = (const float*)d_in[3];
  const float* bk = (const float*)d_in[4];
  const float* Wv = (const float*)d_in[5];
  const float* bv = (const float*)d_in[6];

  char* ws = (char*)d_ws;
  uint16_t* qb   = (uint16_t*)(ws);              //  8 MB  q bf16
  uint16_t* kb   = (uint16_t*)(ws + 8388608);    //  8 MB  k bf16
  uint16_t* vb   = (uint16_t*)(ws + 16777216);   //  8 MB  v bf16
  uint16_t* wt   = (uint16_t*)(ws + 25165824);   // 384 KB WT bf16 (q|k|v transposed)
  float* l_arr   = (float*)(ws + 25559040);      // 64 KB  row sums
  float* w_arr   = (float*)(ws + 25624576);      // 64 KB  col weights (adjacent)
  float* part    = (float*)(ws + 25690112);      // 256 KB pool partials
  float* out     = (float*)d_out;

  hipMemsetAsync(l_arr, 0, 2 * 65536, stream);   // zeros l + w

  wcast_kernel<<<48, 256, 0, stream>>>(Wq, Wk, Wv, wt);
  qkv_kernel<<<256, 256, 0, stream>>>(x, wt, bq, bk, bv, qb, kb, vb);
  scores_l_kernel<<<512, 256, 0, stream>>>(qb, kb, l_arr);
  scores_w_kernel<<<512, 256, 0, stream>>>(qb, kb, l_arr, w_arr);
  pool1_kernel<<<256, 256, 0, stream>>>(w_arr, vb, part);
  pool2_kernel<<<4, 256, 0, stream>>>(part, out);
}

// Round 6
// 180.573 us; speedup vs baseline: 1.2314x; 1.2314x over previous
//
#include <hip/hip_runtime.h>
#include <stdint.h>

#define SS 4096
#define EE 256
// log2(e)/16  (logit scale 1/NORM_FACTOR folded into exp2 conversion)
#define C2 0.0901684400555602f

typedef __bf16 bf16x8 __attribute__((ext_vector_type(8)));
typedef float  f32x4  __attribute__((ext_vector_type(4)));

#if __has_builtin(__builtin_amdgcn_exp2f)
#define EXP2(x) __builtin_amdgcn_exp2f(x)
#else
#define EXP2(x) exp2f(x)
#endif
#if __has_builtin(__builtin_amdgcn_rcpf)
#define RCP(x) __builtin_amdgcn_rcpf(x)
#else
#define RCP(x) (1.0f / (x))
#endif

__device__ __forceinline__ uint16_t bf16_rn(float f) {
  uint32_t u = __float_as_uint(f);
  uint32_t r = (u + 0x7fffu + ((u >> 16) & 1u)) >> 16;
  return (uint16_t)r;
}
__device__ __forceinline__ float bf2f(uint16_t h) {
  return __uint_as_float(((uint32_t)h) << 16);
}
__device__ __forceinline__ bf16x8 pack_bf8(float4 a, float4 b) {
  union { bf16x8 v; uint16_t u[8]; } r;
  r.u[0] = bf16_rn(a.x); r.u[1] = bf16_rn(a.y);
  r.u[2] = bf16_rn(a.z); r.u[3] = bf16_rn(a.w);
  r.u[4] = bf16_rn(b.x); r.u[5] = bf16_rn(b.y);
  r.u[6] = bf16_rn(b.z); r.u[7] = bf16_rn(b.w);
  return r.v;
}

__device__ __forceinline__ f32x4 mfma16(bf16x8 a, bf16x8 b, f32x4 c) {
  return __builtin_amdgcn_mfma_f32_16x16x32_bf16(a, b, c, 0, 0, 0);
}

// Stage R rows x 512B global -> LDS via global_load_lds(16B), 5-bit XOR
// swizzle: logical chunk cc of row r lands at physical chunk cc^(r&31).
// Register-free transport (R2 lesson: global->reg streaming starves VGPRs).
// NOTE (R5 lesson): 32x32 MFMA + per-element exp forces AGPR->VGPR round
// trips (f32x16 accs) and register rematerialization — stay on 16x16.
template<int R>
__device__ __forceinline__ void stage_tile(const uint16_t* gsrc, char* lds, int tid) {
  constexpr int NPER = (R * 32) / 256;
  const int wave = tid >> 6;
  #pragma unroll
  for (int c = 0; c < NPER; ++c) {
    int chunk = c * 256 + tid;
    int r = chunk >> 5;
    int ccl = (chunk & 31) ^ (r & 31);
    const char* gp = (const char*)gsrc + (r * 32 + ccl) * 16;
    char* lp = lds + (c * 256 + wave * 64) * 16;
    __builtin_amdgcn_global_load_lds(
        (const __attribute__((address_space(1))) uint32_t*)(uintptr_t)gp,
        (__attribute__((address_space(3))) uint32_t*)(uintptr_t)lp,
        16, 0, 0);
  }
}

__device__ __forceinline__ bf16x8 read_frag(const char* lds, int row, int cc) {
  int ccp = cc ^ (row & 31);
  return *(const bf16x8*)(lds + (row * 32 + ccp) * 16);
}

// ---------------- K0: prep = W transpose-cast + zero l/w/out ----------------
// blocks 0..47: wcast; blocks 48..80: zero 8448 float4 (l+w then out).
__global__ void prep_kernel(const float* __restrict__ Wq, const float* __restrict__ Wk,
                            const float* __restrict__ Wv, uint16_t* __restrict__ wt,
                            float* __restrict__ zbase, float* __restrict__ out) {
  __shared__ float t[64][65];
  const int bid = blockIdx.x, tid = threadIdx.x;
  if (bid >= 48) {
    int idx = (bid - 48) * 256 + tid;           // float4 index
    float4 z = {0.f, 0.f, 0.f, 0.f};
    if (idx < 8192) ((float4*)zbase)[idx] = z;  // l_arr + w_arr (contiguous)
    else ((float4*)out)[idx - 8192] = z;        // 1024 floats of out
    return;
  }
  const int mat = bid >> 4, tt = bid & 15;
  const int ib = (tt >> 2) * 64, ob = (tt & 3) * 64;
  const float* W = (mat == 0) ? Wq : (mat == 1) ? Wk : Wv;
  #pragma unroll
  for (int p = 0; p < 4; ++p) {
    int idx = p * 256 + tid;
    int r = idx >> 4, c4 = idx & 15;
    float4 f = *(const float4*)&W[(size_t)(ib + r) * 256 + ob + c4 * 4];
    t[r][c4 * 4 + 0] = f.x; t[r][c4 * 4 + 1] = f.y;
    t[r][c4 * 4 + 2] = f.z; t[r][c4 * 4 + 3] = f.w;
  }
  __syncthreads();
  #pragma unroll
  for (int p = 0; p < 4; ++p) {
    int idx = p * 256 + tid;
    int o = idx >> 4, i4 = idx & 15;
    ushort4 u;
    u.x = bf16_rn(t[i4 * 4 + 0][o]);
    u.y = bf16_rn(t[i4 * 4 + 1][o]);
    u.z = bf16_rn(t[i4 * 4 + 2][o]);
    u.w = bf16_rn(t[i4 * 4 + 3][o]);
    *(ushort4*)&wt[((size_t)mat * 256 + ob + o) * 256 + ib + i4 * 4] = u;
  }
}

// ---------------- K1: fused QKV projection GEMM ----------------
// 512 WGs = 128 m-blocks(128 rows) x 4 col-chunks(192) -> 2 WGs/CU (was 1).
__global__ __launch_bounds__(256, 2) void qkv_kernel(
    const float* __restrict__ x, const uint16_t* __restrict__ wt,
    const float* __restrict__ bq, const float* __restrict__ bk, const float* __restrict__ bv,
    uint16_t* __restrict__ qo, uint16_t* __restrict__ ko, uint16_t* __restrict__ vo) {
  __shared__ char wsm[2][32768];
  const int tid = threadIdx.x;
  const int lane = tid & 63, wave = tid >> 6, quad = lane >> 4, lr = lane & 15;
  const int m0 = (blockIdx.x >> 2) * 128;
  const int cchunk = blockIdx.x & 3;          // 4 chunks of 192 cols over [q|k|v]
  stage_tile<64>(wt + (size_t)(cchunk * 192) * 256, wsm[0], tid);
  const float* ab = x + (size_t)(m0 + wave * 32) * EE;
  bf16x8 a[2][8];
  #pragma unroll
  for (int ms = 0; ms < 2; ++ms)
    #pragma unroll
    for (int f = 0; f < 8; ++f) {
      const float* rp = ab + (size_t)(ms * 16 + lr) * EE + f * 32 + quad * 8;
      a[ms][f] = pack_bf8(*(const float4*)rp, *(const float4*)(rp + 4));
    }
  for (int nc = 0; nc < 3; ++nc) {
    __syncthreads();
    if (nc < 2)
      stage_tile<64>(wt + (size_t)(cchunk * 192 + (nc + 1) * 64) * 256, wsm[(nc + 1) & 1], tid);
    const char* tile = wsm[nc & 1];
    #pragma unroll
    for (int nt = 0; nt < 4; ++nt) {
      const int eg0 = cchunk * 192 + nc * 64 + nt * 16;
      const int mat = eg0 >> 8;
      const int e = (eg0 & 255) + lr;
      const float* bias = (mat == 0) ? bq : (mat == 1) ? bk : bv;
      uint16_t* outp = (mat == 0) ? qo : (mat == 1) ? ko : vo;
      bf16x8 bf[8];
      #pragma unroll
      for (int f = 0; f < 8; ++f) bf[f] = read_frag(tile, nt * 16 + lr, f * 4 + quad);
      f32x4 acc[2] = {};
      #pragma unroll
      for (int f = 0; f < 8; ++f)
        #pragma unroll
        for (int ms = 0; ms < 2; ++ms)
          acc[ms] = mfma16(a[ms][f], bf[f], acc[ms]);
      const float bsv = bias[e];
      #pragma unroll
      for (int ms = 0; ms < 2; ++ms)
        #pragma unroll
        for (int r = 0; r < 4; ++r) {
          int row = m0 + wave * 32 + ms * 16 + quad * 4 + r;
          outp[(size_t)row * EE + e] = bf16_rn(acc[ms][r] + bsv);
        }
    }
  }
}

// ---------------- K2: pass A  l[s] = sum_t exp(q_s.k_t/16) ----------------
// 16x16x32 MFMA (R4 structure — ~97% of MFMA roofline). A (64 q-rows/wave)
// resident; K via 64-key dbuf LDS, 8 iters.
__global__ __launch_bounds__(256, 2) void scores_l_kernel(
    const uint16_t* __restrict__ q, const uint16_t* __restrict__ k,
    float* __restrict__ lacc) {
  __shared__ char kt[2][32768];
  const int tid = threadIdx.x;
  const int lane = tid & 63, wave = tid >> 6, quad = lane >> 4, lr = lane & 15;
  const int idx = blockIdx.x;
  const int b = idx >> 7, rem = idx & 127, qblk = rem >> 3, kch = rem & 7;
  const uint16_t* qb = q + (size_t)(b * SS + qblk * 256 + wave * 64) * EE;
  const uint16_t* kb = k + (size_t)(b * SS + kch * 512) * EE;
  stage_tile<64>(kb, kt[0], tid);
  bf16x8 a[4][8];
  #pragma unroll
  for (int ms = 0; ms < 4; ++ms)
    #pragma unroll
    for (int f = 0; f < 8; ++f)
      a[ms][f] = *(const bf16x8*)(qb + (size_t)(ms * 16 + lr) * EE + f * 32 + quad * 8);
  float accl[16];
  #pragma unroll
  for (int i = 0; i < 16; ++i) accl[i] = 0.f;
  for (int it = 0; it < 8; ++it) {
    __syncthreads();                      // stage(it) landed; buf (it-1) free
    if (it + 1 < 8) stage_tile<64>(kb + (size_t)(it + 1) * 64 * EE, kt[(it + 1) & 1], tid);
    const char* tile = kt[it & 1];
    #pragma unroll
    for (int nt = 0; nt < 4; ++nt) {
      bf16x8 bf[8];
      #pragma unroll
      for (int f = 0; f < 8; ++f) bf[f] = read_frag(tile, nt * 16 + lr, f * 4 + quad);
      f32x4 acc[4] = {};
      #pragma unroll
      for (int f = 0; f < 8; ++f)
        #pragma unroll
        for (int ms = 0; ms < 4; ++ms)
          acc[ms] = mfma16(a[ms][f], bf[f], acc[ms]);
      #pragma unroll
      for (int ms = 0; ms < 4; ++ms)
        #pragma unroll
        for (int r = 0; r < 4; ++r)
          accl[ms * 4 + r] += EXP2(acc[ms][r] * C2);
    }
  }
  #pragma unroll
  for (int d = 1; d < 16; d <<= 1)
    #pragma unroll
    for (int i = 0; i < 16; ++i)
      accl[i] += __shfl_xor(accl[i], d, 64);
  if (lr == 0) {
    float* lp = lacc + b * SS + qblk * 256 + wave * 64;
    #pragma unroll
    for (int ms = 0; ms < 4; ++ms)
      #pragma unroll
      for (int r = 0; r < 4; ++r)
        atomicAdd(&lp[ms * 16 + quad * 4 + r], accl[ms * 4 + r]);
  }
}

// ---------------- K3: pass B  w[t] = sum_s exp(q_s.k_t/16) / l[s] ----------
__global__ __launch_bounds__(256, 2) void scores_w_kernel(
    const uint16_t* __restrict__ q, const uint16_t* __restrict__ k,
    const float* __restrict__ lacc, float* __restrict__ wacc) {
  __shared__ char qt[2][32768];
  const int tid = threadIdx.x;
  const int lane = tid & 63, wave = tid >> 6, quad = lane >> 4, lr = lane & 15;
  const int idx = blockIdx.x;
  const int b = idx >> 7, rem = idx & 127, kblk = rem >> 3, sch = rem & 7;
  const uint16_t* kb = k + (size_t)(b * SS + kblk * 256 + wave * 64) * EE;
  const uint16_t* qb = q + (size_t)(b * SS + sch * 512) * EE;
  const float* rlb = lacc + b * SS + sch * 512;
  stage_tile<64>(qb, qt[0], tid);
  bf16x8 a[4][8];
  #pragma unroll
  for (int ms = 0; ms < 4; ++ms)
    #pragma unroll
    for (int f = 0; f < 8; ++f)
      a[ms][f] = *(const bf16x8*)(kb + (size_t)(ms * 16 + lr) * EE + f * 32 + quad * 8);
  float accw[16];
  #pragma unroll
  for (int i = 0; i < 16; ++i) accw[i] = 0.f;
  for (int it = 0; it < 8; ++it) {
    __syncthreads();
    if (it + 1 < 8) stage_tile<64>(qb + (size_t)(it + 1) * 64 * EE, qt[(it + 1) & 1], tid);
    const char* tile = qt[it & 1];
    #pragma unroll
    for (int nt = 0; nt < 4; ++nt) {
      float rlv = RCP(rlb[it * 64 + nt * 16 + lr]);   // 1/l for col s
      bf16x8 bf[8];
      #pragma unroll
      for (int f = 0; f < 8; ++f) bf[f] = read_frag(tile, nt * 16 + lr, f * 4 + quad);
      f32x4 acc[4] = {};
      #pragma unroll
      for (int f = 0; f < 8; ++f)
        #pragma unroll
        for (int ms = 0; ms < 4; ++ms)
          acc[ms] = mfma16(a[ms][f], bf[f], acc[ms]);
      #pragma unroll
      for (int ms = 0; ms < 4; ++ms)
        #pragma unroll
        for (int r = 0; r < 4; ++r)
          accw[ms * 4 + r] += EXP2(acc[ms][r] * C2) * rlv;
    }
  }
  #pragma unroll
  for (int d = 1; d < 16; d <<= 1)
    #pragma unroll
    for (int i = 0; i < 16; ++i)
      accw[i] += __shfl_xor(accw[i], d, 64);
  if (lr == 0) {
    float* wp = wacc + b * SS + kblk * 256 + wave * 64;
    #pragma unroll
    for (int ms = 0; ms < 4; ++ms)
      #pragma unroll
      for (int r = 0; r < 4; ++r)
        atomicAdd(&wp[ms * 16 + quad * 4 + r], accw[ms * 4 + r]);
  }
}

// ---------------- K4: pool — out[b,e] += (1/S) sum_t w[t] v[t,e] ------------
// 256 blocks; fully-unrolled 16 loads/thread; LDS wave-reduce; atomic finish
// into out (zeroed by prep).
__global__ void pool_kernel(const float* __restrict__ wsum, const uint16_t* __restrict__ v,
                            float* __restrict__ out) {
  __shared__ float red[4][256];
  const int b = blockIdx.x >> 6, tc = blockIdx.x & 63;
  const int tq = threadIdx.x >> 6, eg = threadIdx.x & 63;
  float acc[4] = {0.f, 0.f, 0.f, 0.f};
  const float* wp = wsum + b * SS + tc * 64;
  const uint16_t* vp = v + (size_t)(b * SS + tc * 64) * EE + eg * 4;
  #pragma unroll
  for (int t = 0; t < 16; ++t) {
    int row = t * 4 + tq;
    float wv = wp[row];
    ushort4 x4 = *(const ushort4*)(vp + (size_t)row * EE);
    acc[0] += wv * bf2f(x4.x);
    acc[1] += wv * bf2f(x4.y);
    acc[2] += wv * bf2f(x4.z);
    acc[3] += wv * bf2f(x4.w);
  }
  #pragma unroll
  for (int j = 0; j < 4; ++j) red[tq][eg * 4 + j] = acc[j];
  __syncthreads();
  if (tq == 0) {
    const float inv = 1.0f / 4096.0f;
    #pragma unroll
    for (int j = 0; j < 4; ++j) {
      float s = red[0][eg * 4 + j] + red[1][eg * 4 + j] +
                red[2][eg * 4 + j] + red[3][eg * 4 + j];
      atomicAdd(&out[b * 256 + eg * 4 + j], s * inv);
    }
  }
}

// ---------------- launch ----------------
extern "C" void kernel_launch(void* const* d_in, const int* in_sizes, int n_in,
                              void* d_out, int out_size, void* d_ws, size_t ws_size,
                              hipStream_t stream) {
  const float* x  = (const float*)d_in[0];
  const float* Wq = (const float*)d_in[1];
  const float* bq = (const float*)d_in[2];
  const float* Wk = (const float*)d_in[3];
  const float* bk = (const float*)d_in[4];
  const float* Wv = (const float*)d_in[5];
  const float* bv = (const float*)d_in[6];

  char* ws = (char*)d_ws;
  uint16_t* qb   = (uint16_t*)(ws);              //  8 MB  q bf16
  uint16_t* kb   = (uint16_t*)(ws + 8388608);    //  8 MB  k bf16
  uint16_t* vb   = (uint16_t*)(ws + 16777216);   //  8 MB  v bf16
  uint16_t* wt   = (uint16_t*)(ws + 25165824);   // 384 KB WT bf16 (q|k|v transposed)
  float* l_arr   = (float*)(ws + 25559040);      // 64 KB  row sums
  float* w_arr   = (float*)(ws + 25624576);      // 64 KB  col weights (contiguous after l)
  float* out     = (float*)d_out;

  prep_kernel<<<81, 256, 0, stream>>>(Wq, Wk, Wv, wt, l_arr, out);
  qkv_kernel<<<512, 256, 0, stream>>>(x, wt, bq, bk, bv, qb, kb, vb);
  scores_l_kernel<<<512, 256, 0, stream>>>(qb, kb, l_arr);
  scores_w_kernel<<<512, 256, 0, stream>>>(qb, kb, l_arr, w_arr);
  pool_kernel<<<256, 256, 0, stream>>>(w_arr, vb, out);
}

// Round 7
// 177.399 us; speedup vs baseline: 1.2534x; 1.0179x over previous
//
#include <hip/hip_runtime.h>
#include <stdint.h>

#define SS 4096
#define EE 256
// log2(e)/16  (logit scale 1/NORM_FACTOR folded into exp2 conversion)
#define C2 0.0901684400555602f

// s_waitcnt immediates (gfx9 encoding: vm[3:0]|exp[6:4]|lgkm[11:8]|vm[15:14])
#define VMCNT0 0x0F70   // wait vmcnt<=0, ignore lgkm/exp
#define VMCNT8 0x0F78   // wait vmcnt<=8
#define LGKM0  0xC07F   // wait lgkmcnt<=0, ignore vm/exp
#define WAITCNT(imm) __builtin_amdgcn_s_waitcnt(imm)

typedef __bf16 bf16x8 __attribute__((ext_vector_type(8)));
typedef float  f32x4  __attribute__((ext_vector_type(4)));

#if __has_builtin(__builtin_amdgcn_exp2f)
#define EXP2(x) __builtin_amdgcn_exp2f(x)
#else
#define EXP2(x) exp2f(x)
#endif
#if __has_builtin(__builtin_amdgcn_rcpf)
#define RCP(x) __builtin_amdgcn_rcpf(x)
#else
#define RCP(x) (1.0f / (x))
#endif

__device__ __forceinline__ uint16_t bf16_rn(float f) {
  uint32_t u = __float_as_uint(f);
  uint32_t r = (u + 0x7fffu + ((u >> 16) & 1u)) >> 16;
  return (uint16_t)r;
}
__device__ __forceinline__ float bf2f(uint16_t h) {
  return __uint_as_float(((uint32_t)h) << 16);
}
__device__ __forceinline__ bf16x8 pack_bf8(float4 a, float4 b) {
  union { bf16x8 v; uint16_t u[8]; } r;
  r.u[0] = bf16_rn(a.x); r.u[1] = bf16_rn(a.y);
  r.u[2] = bf16_rn(a.z); r.u[3] = bf16_rn(a.w);
  r.u[4] = bf16_rn(b.x); r.u[5] = bf16_rn(b.y);
  r.u[6] = bf16_rn(b.z); r.u[7] = bf16_rn(b.w);
  return r.v;
}

__device__ __forceinline__ f32x4 mfma16(bf16x8 a, bf16x8 b, f32x4 c) {
  return __builtin_amdgcn_mfma_f32_16x16x32_bf16(a, b, c, 0, 0, 0);
}

// ---- block-shared staging (qkv): 5-bit XOR swizzle, 256 threads ----
template<int R>
__device__ __forceinline__ void stage_tile(const uint16_t* gsrc, char* lds, int tid) {
  constexpr int NPER = (R * 32) / 256;
  const int wave = tid >> 6;
  #pragma unroll
  for (int c = 0; c < NPER; ++c) {
    int chunk = c * 256 + tid;
    int r = chunk >> 5;
    int ccl = (chunk & 31) ^ (r & 31);
    const char* gp = (const char*)gsrc + (r * 32 + ccl) * 16;
    char* lp = lds + (c * 256 + wave * 64) * 16;
    __builtin_amdgcn_global_load_lds(
        (const __attribute__((address_space(1))) uint32_t*)(uintptr_t)gp,
        (__attribute__((address_space(3))) uint32_t*)(uintptr_t)lp,
        16, 0, 0);
  }
}
__device__ __forceinline__ bf16x8 read_frag(const char* lds, int row, int cc) {
  int ccp = cc ^ (row & 31);
  return *(const bf16x8*)(lds + (row * 32 + ccp) * 16);
}

// ---- per-WAVE staging (scores): 16 rows x 512B = 8 KB, 8 insts/wave,
// 3-bit XOR swizzle. No barriers: wave self-syncs with s_waitcnt vmcnt(N).
__device__ __forceinline__ void stage16(const uint16_t* gsrc, char* lds, int lane) {
  #pragma unroll
  for (int c = 0; c < 8; ++c) {
    int p = c * 64 + lane;                // physical chunk 0..511
    int r = p >> 5;
    int ccl = (p & 31) ^ (r & 7);
    const char* gp = (const char*)gsrc + (r * 32 + ccl) * 16;
    char* lp = lds + c * 1024;            // wave-uniform; HW adds lane*16
    __builtin_amdgcn_global_load_lds(
        (const __attribute__((address_space(1))) uint32_t*)(uintptr_t)gp,
        (__attribute__((address_space(3))) uint32_t*)(uintptr_t)lp,
        16, 0, 0);
  }
}
__device__ __forceinline__ bf16x8 read_frag16(const char* lds, int row, int cc) {
  int ccp = cc ^ (row & 7);
  return *(const bf16x8*)(lds + (row * 32 + ccp) * 16);
}

// ---------------- K0: prep = W transpose-cast + zero l/w/out ----------------
__global__ void prep_kernel(const float* __restrict__ Wq, const float* __restrict__ Wk,
                            const float* __restrict__ Wv, uint16_t* __restrict__ wt,
                            float* __restrict__ zbase, float* __restrict__ out) {
  __shared__ float t[64][65];
  const int bid = blockIdx.x, tid = threadIdx.x;
  if (bid >= 48) {
    int idx = (bid - 48) * 256 + tid;
    float4 z = {0.f, 0.f, 0.f, 0.f};
    if (idx < 8192) ((float4*)zbase)[idx] = z;
    else ((float4*)out)[idx - 8192] = z;
    return;
  }
  const int mat = bid >> 4, tt = bid & 15;
  const int ib = (tt >> 2) * 64, ob = (tt & 3) * 64;
  const float* W = (mat == 0) ? Wq : (mat == 1) ? Wk : Wv;
  #pragma unroll
  for (int p = 0; p < 4; ++p) {
    int idx = p * 256 + tid;
    int r = idx >> 4, c4 = idx & 15;
    float4 f = *(const float4*)&W[(size_t)(ib + r) * 256 + ob + c4 * 4];
    t[r][c4 * 4 + 0] = f.x; t[r][c4 * 4 + 1] = f.y;
    t[r][c4 * 4 + 2] = f.z; t[r][c4 * 4 + 3] = f.w;
  }
  __syncthreads();
  #pragma unroll
  for (int p = 0; p < 4; ++p) {
    int idx = p * 256 + tid;
    int o = idx >> 4, i4 = idx & 15;
    ushort4 u;
    u.x = bf16_rn(t[i4 * 4 + 0][o]);
    u.y = bf16_rn(t[i4 * 4 + 1][o]);
    u.z = bf16_rn(t[i4 * 4 + 2][o]);
    u.w = bf16_rn(t[i4 * 4 + 3][o]);
    *(ushort4*)&wt[((size_t)mat * 256 + ob + o) * 256 + ib + i4 * 4] = u;
  }
}

// ---------------- K1: fused QKV projection GEMM ----------------
__global__ __launch_bounds__(256, 2) void qkv_kernel(
    const float* __restrict__ x, const uint16_t* __restrict__ wt,
    const float* __restrict__ bq, const float* __restrict__ bk, const float* __restrict__ bv,
    uint16_t* __restrict__ qo, uint16_t* __restrict__ ko, uint16_t* __restrict__ vo) {
  __shared__ char wsm[2][32768];
  const int tid = threadIdx.x;
  const int lane = tid & 63, wave = tid >> 6, quad = lane >> 4, lr = lane & 15;
  const int m0 = (blockIdx.x >> 2) * 128;
  const int cchunk = blockIdx.x & 3;
  stage_tile<64>(wt + (size_t)(cchunk * 192) * 256, wsm[0], tid);
  const float* ab = x + (size_t)(m0 + wave * 32) * EE;
  bf16x8 a[2][8];
  #pragma unroll
  for (int ms = 0; ms < 2; ++ms)
    #pragma unroll
    for (int f = 0; f < 8; ++f) {
      const float* rp = ab + (size_t)(ms * 16 + lr) * EE + f * 32 + quad * 8;
      a[ms][f] = pack_bf8(*(const float4*)rp, *(const float4*)(rp + 4));
    }
  for (int nc = 0; nc < 3; ++nc) {
    __syncthreads();
    if (nc < 2)
      stage_tile<64>(wt + (size_t)(cchunk * 192 + (nc + 1) * 64) * 256, wsm[(nc + 1) & 1], tid);
    const char* tile = wsm[nc & 1];
    #pragma unroll
    for (int nt = 0; nt < 4; ++nt) {
      const int eg0 = cchunk * 192 + nc * 64 + nt * 16;
      const int mat = eg0 >> 8;
      const int e = (eg0 & 255) + lr;
      const float* bias = (mat == 0) ? bq : (mat == 1) ? bk : bv;
      uint16_t* outp = (mat == 0) ? qo : (mat == 1) ? ko : vo;
      bf16x8 bf[8];
      #pragma unroll
      for (int f = 0; f < 8; ++f) bf[f] = read_frag(tile, nt * 16 + lr, f * 4 + quad);
      f32x4 acc[2] = {};
      #pragma unroll
      for (int f = 0; f < 8; ++f)
        #pragma unroll
        for (int ms = 0; ms < 2; ++ms)
          acc[ms] = mfma16(a[ms][f], bf[f], acc[ms]);
      const float bsv = bias[e];
      #pragma unroll
      for (int ms = 0; ms < 2; ++ms)
        #pragma unroll
        for (int r = 0; r < 4; ++r) {
          int row = m0 + wave * 32 + ms * 16 + quad * 4 + r;
          outp[(size_t)row * EE + e] = bf16_rn(acc[ms][r] + bsv);
        }
    }
  }
}

// ---------------- K2: pass A  l[s] = sum_t exp(q_s.k_t/16) ----------------
// Barrier-free per-wave pipeline: each wave owns 64 q-rows (regs) + a
// private 2x8KB LDS dbuf; streams all 512 keys in 32 16-key tiles with
// explicit vmcnt(8) self-sync (AITER-style; no __syncthreads in loop).
__global__ __launch_bounds__(256, 2) void scores_l_kernel(
    const uint16_t* __restrict__ q, const uint16_t* __restrict__ k,
    float* __restrict__ lacc) {
  __shared__ char kt[4][2][8192];
  const int tid = threadIdx.x;
  const int lane = tid & 63, wave = tid >> 6, quad = lane >> 4, lr = lane & 15;
  const int idx = blockIdx.x;
  const int b = idx >> 7, rem = idx & 127, qblk = rem >> 3, kch = rem & 7;
  const uint16_t* qb = q + (size_t)(b * SS + qblk * 256 + wave * 64) * EE;
  const uint16_t* kw = k + (size_t)(b * SS + kch * 512) * EE;
  bf16x8 a[4][8];
  #pragma unroll
  for (int ms = 0; ms < 4; ++ms)
    #pragma unroll
    for (int f = 0; f < 8; ++f)
      a[ms][f] = *(const bf16x8*)(qb + (size_t)(ms * 16 + lr) * EE + f * 32 + quad * 8);
  stage16(kw, kt[wave][0], lane);
  stage16(kw + 16 * EE, kt[wave][1], lane);
  float accl[16];
  #pragma unroll
  for (int i = 0; i < 16; ++i) accl[i] = 0.f;
  #pragma unroll 2
  for (int t = 0; t < 32; ++t) {
    if (t == 31) WAITCNT(VMCNT0); else WAITCNT(VMCNT8);   // tile t landed
    const char* tile = kt[wave][t & 1];
    bf16x8 bf[8];
    #pragma unroll
    for (int f = 0; f < 8; ++f) bf[f] = read_frag16(tile, lr, f * 4 + quad);
    f32x4 acc[4] = {};
    #pragma unroll
    for (int f = 0; f < 8; ++f)
      #pragma unroll
      for (int ms = 0; ms < 4; ++ms)
        acc[ms] = mfma16(a[ms][f], bf[f], acc[ms]);
    if (t + 2 < 32) {
      WAITCNT(LGKM0);                   // bf reads drained before overwrite
      stage16(kw + (size_t)(t + 2) * 16 * EE, kt[wave][t & 1], lane);
    }
    #pragma unroll
    for (int ms = 0; ms < 4; ++ms)
      #pragma unroll
      for (int r = 0; r < 4; ++r)
        accl[ms * 4 + r] += EXP2(acc[ms][r] * C2);
  }
  #pragma unroll
  for (int d = 1; d < 16; d <<= 1)
    #pragma unroll
    for (int i = 0; i < 16; ++i)
      accl[i] += __shfl_xor(accl[i], d, 64);
  if (lr == 0) {
    float* lp = lacc + b * SS + qblk * 256 + wave * 64;
    #pragma unroll
    for (int ms = 0; ms < 4; ++ms)
      #pragma unroll
      for (int r = 0; r < 4; ++r)
        atomicAdd(&lp[ms * 16 + quad * 4 + r], accl[ms * 4 + r]);
  }
}

// ---------------- K3: pass B  w[t] = sum_s exp(q_s.k_t/16) / l[s] ----------
// Mirror of K2; rl (1/l per streamed query col) read from a small LDS copy
// so the hot loop issues no extra vmem (keeps vmcnt arithmetic exact).
__global__ __launch_bounds__(256, 2) void scores_w_kernel(
    const uint16_t* __restrict__ q, const uint16_t* __restrict__ k,
    const float* __restrict__ lacc, float* __restrict__ wacc) {
  __shared__ char qt[4][2][8192];
  __shared__ float rls[512];
  const int tid = threadIdx.x;
  const int lane = tid & 63, wave = tid >> 6, quad = lane >> 4, lr = lane & 15;
  const int idx = blockIdx.x;
  const int b = idx >> 7, rem = idx & 127, kblk = rem >> 3, sch = rem & 7;
  const uint16_t* kb = k + (size_t)(b * SS + kblk * 256 + wave * 64) * EE;
  const uint16_t* qw = q + (size_t)(b * SS + sch * 512) * EE;
  const float* rlb = lacc + b * SS + sch * 512;
  ((float2*)rls)[tid] = ((const float2*)rlb)[tid];    // 512 floats
  bf16x8 a[4][8];
  #pragma unroll
  for (int ms = 0; ms < 4; ++ms)
    #pragma unroll
    for (int f = 0; f < 8; ++f)
      a[ms][f] = *(const bf16x8*)(kb + (size_t)(ms * 16 + lr) * EE + f * 32 + quad * 8);
  __syncthreads();                                    // rls visible; pre-loop only
  stage16(qw, qt[wave][0], lane);
  stage16(qw + 16 * EE, qt[wave][1], lane);
  float accw[16];
  #pragma unroll
  for (int i = 0; i < 16; ++i) accw[i] = 0.f;
  #pragma unroll 2
  for (int t = 0; t < 32; ++t) {
    if (t == 31) WAITCNT(VMCNT0); else WAITCNT(VMCNT8);
    const char* tile = qt[wave][t & 1];
    float rlv = RCP(rls[t * 16 + lr]);                // 1/l for col s
    bf16x8 bf[8];
    #pragma unroll
    for (int f = 0; f < 8; ++f) bf[f] = read_frag16(tile, lr, f * 4 + quad);
    f32x4 acc[4] = {};
    #pragma unroll
    for (int f = 0; f < 8; ++f)
      #pragma unroll
      for (int ms = 0; ms < 4; ++ms)
        acc[ms] = mfma16(a[ms][f], bf[f], acc[ms]);
    if (t + 2 < 32) {
      WAITCNT(LGKM0);
      stage16(qw + (size_t)(t + 2) * 16 * EE, qt[wave][t & 1], lane);
    }
    #pragma unroll
    for (int ms = 0; ms < 4; ++ms)
      #pragma unroll
      for (int r = 0; r < 4; ++r)
        accw[ms * 4 + r] += EXP2(acc[ms][r] * C2) * rlv;
  }
  #pragma unroll
  for (int d = 1; d < 16; d <<= 1)
    #pragma unroll
    for (int i = 0; i < 16; ++i)
      accw[i] += __shfl_xor(accw[i], d, 64);
  if (lr == 0) {
    float* wp = wacc + b * SS + kblk * 256 + wave * 64;
    #pragma unroll
    for (int ms = 0; ms < 4; ++ms)
      #pragma unroll
      for (int r = 0; r < 4; ++r)
        atomicAdd(&wp[ms * 16 + quad * 4 + r], accw[ms * 4 + r]);
  }
}

// ---------------- K4: pool — out[b,e] += (1/S) sum_t w[t] v[t,e] ------------
__global__ void pool_kernel(const float* __restrict__ wsum, const uint16_t* __restrict__ v,
                            float* __restrict__ out) {
  __shared__ float red[4][256];
  const int b = blockIdx.x >> 6, tc = blockIdx.x & 63;
  const int tq = threadIdx.x >> 6, eg = threadIdx.x & 63;
  float acc[4] = {0.f, 0.f, 0.f, 0.f};
  const float* wp = wsum + b * SS + tc * 64;
  const uint16_t* vp = v + (size_t)(b * SS + tc * 64) * EE + eg * 4;
  #pragma unroll
  for (int t = 0; t < 16; ++t) {
    int row = t * 4 + tq;
    float wv = wp[row];
    ushort4 x4 = *(const ushort4*)(vp + (size_t)row * EE);
    acc[0] += wv * bf2f(x4.x);
    acc[1] += wv * bf2f(x4.y);
    acc[2] += wv * bf2f(x4.z);
    acc[3] += wv * bf2f(x4.w);
  }
  #pragma unroll
  for (int j = 0; j < 4; ++j) red[tq][eg * 4 + j] = acc[j];
  __syncthreads();
  if (tq == 0) {
    const float inv = 1.0f / 4096.0f;
    #pragma unroll
    for (int j = 0; j < 4; ++j) {
      float s = red[0][eg * 4 + j] + red[1][eg * 4 + j] +
                red[2][eg * 4 + j] + red[3][eg * 4 + j];
      atomicAdd(&out[b * 256 + eg * 4 + j], s * inv);
    }
  }
}

// ---------------- launch ----------------
extern "C" void kernel_launch(void* const* d_in, const int* in_sizes, int n_in,
                              void* d_out, int out_size, void* d_ws, size_t ws_size,
                              hipStream_t stream) {
  const float* x  = (const float*)d_in[0];
  const float* Wq = (const float*)d_in[1];
  const float* bq = (const float*)d_in[2];
  const float* Wk = (const float*)d_in[3];
  const float* bk = (const float*)d_in[4];
  const float* Wv = (const float*)d_in[5];
  const float* bv = (const float*)d_in[6];

  char* ws = (char*)d_ws;
  uint16_t* qb   = (uint16_t*)(ws);              //  8 MB  q bf16
  uint16_t* kb   = (uint16_t*)(ws + 8388608);    //  8 MB  k bf16
  uint16_t* vb   = (uint16_t*)(ws + 16777216);   //  8 MB  v bf16
  uint16_t* wt   = (uint16_t*)(ws + 25165824);   // 384 KB WT bf16
  float* l_arr   = (float*)(ws + 25559040);      // 64 KB  row sums
  float* w_arr   = (float*)(ws + 25624576);      // 64 KB  col weights
  float* out     = (float*)d_out;

  prep_kernel<<<81, 256, 0, stream>>>(Wq, Wk, Wv, wt, l_arr, out);
  qkv_kernel<<<512, 256, 0, stream>>>(x, wt, bq, bk, bv, qb, kb, vb);
  scores_l_kernel<<<512, 256, 0, stream>>>(qb, kb, l_arr);
  scores_w_kernel<<<512, 256, 0, stream>>>(qb, kb, l_arr, w_arr);
  pool_kernel<<<256, 256, 0, stream>>>(w_arr, vb, out);
}

// Round 8
// 152.983 us; speedup vs baseline: 1.4535x; 1.1596x over previous
//
#include <hip/hip_runtime.h>
#include <hip/hip_fp8.h>
#include <stdint.h>

#define SS 4096
#define EE 256
// log2(e)/16  (logit scale 1/NORM_FACTOR folded into exp2 conversion)
#define C2 0.0901684400555602f
#define SCALE1 0x7F7F7F7F   // E8M0 exponent 127 = 1.0 in every byte

typedef __bf16 bf16x8 __attribute__((ext_vector_type(8)));
typedef float  f32x4  __attribute__((ext_vector_type(4)));
typedef int    i32x8  __attribute__((ext_vector_type(8)));

#if __has_builtin(__builtin_amdgcn_exp2f)
#define EXP2(x) __builtin_amdgcn_exp2f(x)
#else
#define EXP2(x) exp2f(x)
#endif
#if __has_builtin(__builtin_amdgcn_rcpf)
#define RCP(x) __builtin_amdgcn_rcpf(x)
#else
#define RCP(x) (1.0f / (x))
#endif

__device__ __forceinline__ uint16_t bf16_rn(float f) {
  uint32_t u = __float_as_uint(f);
  uint32_t r = (u + 0x7fffu + ((u >> 16) & 1u)) >> 16;
  return (uint16_t)r;
}
__device__ __forceinline__ float bf2f(uint16_t h) {
  return __uint_as_float(((uint32_t)h) << 16);
}
__device__ __forceinline__ bf16x8 pack_bf8(float4 a, float4 b) {
  union { bf16x8 v; uint16_t u[8]; } r;
  r.u[0] = bf16_rn(a.x); r.u[1] = bf16_rn(a.y);
  r.u[2] = bf16_rn(a.z); r.u[3] = bf16_rn(a.w);
  r.u[4] = bf16_rn(b.x); r.u[5] = bf16_rn(b.y);
  r.u[6] = bf16_rn(b.z); r.u[7] = bf16_rn(b.w);
  return r.v;
}
__device__ __forceinline__ uint8_t f32_to_e4m3(float x) {
#if __has_builtin(__builtin_amdgcn_cvt_pk_fp8_f32)
  return (uint8_t)(__builtin_amdgcn_cvt_pk_fp8_f32(x, 0.f, 0, false) & 0xff);
#else
  __hip_fp8_e4m3 h(x);
  return (uint8_t)h.__x;
#endif
}

__device__ __forceinline__ f32x4 mfma16(bf16x8 a, bf16x8 b, f32x4 c) {
  return __builtin_amdgcn_mfma_f32_16x16x32_bf16(a, b, c, 0, 0, 0);
}
// MX-scaled fp8 MFMA, K=128, scales fixed to 1.0 -> plain fp8 GEMM at 2x rate.
__device__ __forceinline__ f32x4 mfma128(i32x8 a, i32x8 b, f32x4 c) {
  return __builtin_amdgcn_mfma_scale_f32_16x16x128_f8f6f4(
      a, b, c, 0 /*fmtA=fp8*/, 0 /*fmtB=fp8*/, 0, SCALE1, 0, SCALE1);
}

// ---- bf16 block staging (qkv W tiles): rows of 512B, 5-bit XOR swizzle ----
template<int R>
__device__ __forceinline__ void stage_tile(const uint16_t* gsrc, char* lds, int tid) {
  constexpr int NPER = (R * 32) / 256;
  const int wave = tid >> 6;
  #pragma unroll
  for (int c = 0; c < NPER; ++c) {
    int chunk = c * 256 + tid;
    int r = chunk >> 5;
    int ccl = (chunk & 31) ^ (r & 31);
    const char* gp = (const char*)gsrc + (r * 32 + ccl) * 16;
    char* lp = lds + (c * 256 + wave * 64) * 16;
    __builtin_amdgcn_global_load_lds(
        (const __attribute__((address_space(1))) uint32_t*)(uintptr_t)gp,
        (__attribute__((address_space(3))) uint32_t*)(uintptr_t)lp,
        16, 0, 0);
  }
}
__device__ __forceinline__ bf16x8 read_frag(const char* lds, int row, int cc) {
  int ccp = cc ^ (row & 31);
  return *(const bf16x8*)(lds + (row * 32 + ccp) * 16);
}

// ---- fp8 block staging (scores): 64 rows x 256B = 16KB, 4-bit XOR swizzle
// (16 chunks of 16B per row; physical chunk = logical ^ (row&15)).
__device__ __forceinline__ void stage_fp8_64(const uint8_t* gsrc, char* lds, int tid) {
  #pragma unroll
  for (int c = 0; c < 4; ++c) {
    int chunk = c * 256 + tid;
    int r = chunk >> 4;
    int ccl = (chunk & 15) ^ (r & 15);
    const char* gp = (const char*)gsrc + (r * 16 + ccl) * 16;
    char* lp = lds + (c * 256 + (tid >> 6) * 64) * 16;
    __builtin_amdgcn_global_load_lds(
        (const __attribute__((address_space(1))) uint32_t*)(uintptr_t)gp,
        (__attribute__((address_space(3))) uint32_t*)(uintptr_t)lp,
        16, 0, 0);
  }
}
// Read 32B B-frag (row t, k-window win, quad) as two swizzled 16B chunks.
__device__ __forceinline__ i32x8 read_frag8(const char* lds, int t, int win, int quad) {
  union { i32x8 v; uint4 q[2]; } r;
  int cc0 = win * 8 + quad * 2;
  r.q[0] = *(const uint4*)(lds + (t * 16 + ((cc0 + 0) ^ (t & 15))) * 16);
  r.q[1] = *(const uint4*)(lds + (t * 16 + ((cc0 + 1) ^ (t & 15))) * 16);
  return r.v;
}

// ---------------- K0: prep = W transpose-cast + zero l/w/out ----------------
__global__ void prep_kernel(const float* __restrict__ Wq, const float* __restrict__ Wk,
                            const float* __restrict__ Wv, uint16_t* __restrict__ wt,
                            float* __restrict__ zbase, float* __restrict__ out) {
  __shared__ float t[64][65];
  const int bid = blockIdx.x, tid = threadIdx.x;
  if (bid >= 48) {
    int idx = (bid - 48) * 256 + tid;
    float4 z = {0.f, 0.f, 0.f, 0.f};
    if (idx < 8192) ((float4*)zbase)[idx] = z;
    else ((float4*)out)[idx - 8192] = z;
    return;
  }
  const int mat = bid >> 4, tt = bid & 15;
  const int ib = (tt >> 2) * 64, ob = (tt & 3) * 64;
  const float* W = (mat == 0) ? Wq : (mat == 1) ? Wk : Wv;
  #pragma unroll
  for (int p = 0; p < 4; ++p) {
    int idx = p * 256 + tid;
    int r = idx >> 4, c4 = idx & 15;
    float4 f = *(const float4*)&W[(size_t)(ib + r) * 256 + ob + c4 * 4];
    t[r][c4 * 4 + 0] = f.x; t[r][c4 * 4 + 1] = f.y;
    t[r][c4 * 4 + 2] = f.z; t[r][c4 * 4 + 3] = f.w;
  }
  __syncthreads();
  #pragma unroll
  for (int p = 0; p < 4; ++p) {
    int idx = p * 256 + tid;
    int o = idx >> 4, i4 = idx & 15;
    ushort4 u;
    u.x = bf16_rn(t[i4 * 4 + 0][o]);
    u.y = bf16_rn(t[i4 * 4 + 1][o]);
    u.z = bf16_rn(t[i4 * 4 + 2][o]);
    u.w = bf16_rn(t[i4 * 4 + 3][o]);
    *(ushort4*)&wt[((size_t)mat * 256 + ob + o) * 256 + ib + i4 * 4] = u;
  }
}

// ---------------- K1: fused QKV projection GEMM ----------------
// q,k written as fp8 e4m3 (for MX-fp8 scores); v as bf16 (for pool).
__global__ __launch_bounds__(256, 2) void qkv_kernel(
    const float* __restrict__ x, const uint16_t* __restrict__ wt,
    const float* __restrict__ bq, const float* __restrict__ bk, const float* __restrict__ bv,
    uint8_t* __restrict__ q8, uint8_t* __restrict__ k8, uint16_t* __restrict__ vo) {
  __shared__ char wsm[2][32768];
  const int tid = threadIdx.x;
  const int lane = tid & 63, wave = tid >> 6, quad = lane >> 4, lr = lane & 15;
  const int m0 = (blockIdx.x >> 2) * 128;
  const int cchunk = blockIdx.x & 3;
  stage_tile<64>(wt + (size_t)(cchunk * 192) * 256, wsm[0], tid);
  const float* ab = x + (size_t)(m0 + wave * 32) * EE;
  bf16x8 a[2][8];
  #pragma unroll
  for (int ms = 0; ms < 2; ++ms)
    #pragma unroll
    for (int f = 0; f < 8; ++f) {
      const float* rp = ab + (size_t)(ms * 16 + lr) * EE + f * 32 + quad * 8;
      a[ms][f] = pack_bf8(*(const float4*)rp, *(const float4*)(rp + 4));
    }
  for (int nc = 0; nc < 3; ++nc) {
    __syncthreads();
    if (nc < 2)
      stage_tile<64>(wt + (size_t)(cchunk * 192 + (nc + 1) * 64) * 256, wsm[(nc + 1) & 1], tid);
    const char* tile = wsm[nc & 1];
    #pragma unroll
    for (int nt = 0; nt < 4; ++nt) {
      const int eg0 = cchunk * 192 + nc * 64 + nt * 16;
      const int mat = eg0 >> 8;
      const int e = (eg0 & 255) + lr;
      const float* bias = (mat == 0) ? bq : (mat == 1) ? bk : bv;
      bf16x8 bf[8];
      #pragma unroll
      for (int f = 0; f < 8; ++f) bf[f] = read_frag(tile, nt * 16 + lr, f * 4 + quad);
      f32x4 acc[2] = {};
      #pragma unroll
      for (int f = 0; f < 8; ++f)
        #pragma unroll
        for (int ms = 0; ms < 2; ++ms)
          acc[ms] = mfma16(a[ms][f], bf[f], acc[ms]);
      const float bsv = bias[e];
      #pragma unroll
      for (int ms = 0; ms < 2; ++ms)
        #pragma unroll
        for (int r = 0; r < 4; ++r) {
          int row = m0 + wave * 32 + ms * 16 + quad * 4 + r;
          float vl = acc[ms][r] + bsv;
          if (mat == 2)      vo[(size_t)row * EE + e] = bf16_rn(vl);
          else if (mat == 1) k8[(size_t)row * EE + e] = f32_to_e4m3(vl);
          else               q8[(size_t)row * EE + e] = f32_to_e4m3(vl);
        }
    }
  }
}

// ---------------- K2: pass A  l[s] = sum_t exp(q_s.k_t/16) ----------------
// MX-fp8 K=128 MFMA (m148: 1.86x over bf16 plateau). A = 64 q-rows/wave in
// 64 VGPRs (fp8, 2 k-windows); K streamed via 64-key (16KB) dbuf LDS.
// Grid 1024 = 4b x 16 qblk(256) x 16 kch(256 keys); 3 blocks/CU.
__global__ __launch_bounds__(256, 3) void scores_l_kernel(
    const uint8_t* __restrict__ q8, const uint8_t* __restrict__ k8,
    float* __restrict__ lacc) {
  __shared__ char kt[2][16384];
  const int tid = threadIdx.x;
  const int lane = tid & 63, wave = tid >> 6, quad = lane >> 4, lr = lane & 15;
  const int idx = blockIdx.x;
  const int b = idx >> 8, rem = idx & 255, qblk = rem >> 4, kch = rem & 15;
  const uint8_t* qb = q8 + (size_t)(b * SS + qblk * 256 + wave * 64) * EE;
  const uint8_t* kb = k8 + (size_t)(b * SS + kch * 256) * EE;
  stage_fp8_64(kb, kt[0], tid);
  i32x8 a[4][2];
  #pragma unroll
  for (int ms = 0; ms < 4; ++ms)
    #pragma unroll
    for (int win = 0; win < 2; ++win)
      a[ms][win] = *(const i32x8*)(qb + (size_t)(ms * 16 + lr) * EE + win * 128 + quad * 32);
  float accl[16];
  #pragma unroll
  for (int i = 0; i < 16; ++i) accl[i] = 0.f;
  for (int it = 0; it < 4; ++it) {
    __syncthreads();                      // stage(it) landed; buf (it-1) free
    if (it + 1 < 4) stage_fp8_64(kb + (size_t)(it + 1) * 64 * EE, kt[(it + 1) & 1], tid);
    const char* tile = kt[it & 1];
    #pragma unroll
    for (int nt = 0; nt < 4; ++nt) {
      i32x8 bf0 = read_frag8(tile, nt * 16 + lr, 0, quad);
      i32x8 bf1 = read_frag8(tile, nt * 16 + lr, 1, quad);
      f32x4 acc[4] = {};
      #pragma unroll
      for (int ms = 0; ms < 4; ++ms) {
        acc[ms] = mfma128(a[ms][0], bf0, acc[ms]);
        acc[ms] = mfma128(a[ms][1], bf1, acc[ms]);
      }
      #pragma unroll
      for (int ms = 0; ms < 4; ++ms)
        #pragma unroll
        for (int r = 0; r < 4; ++r)
          accl[ms * 4 + r] += EXP2(acc[ms][r] * C2);
    }
  }
  #pragma unroll
  for (int d = 1; d < 16; d <<= 1)
    #pragma unroll
    for (int i = 0; i < 16; ++i)
      accl[i] += __shfl_xor(accl[i], d, 64);
  if (lr == 0) {
    float* lp = lacc + b * SS + qblk * 256 + wave * 64;
    #pragma unroll
    for (int ms = 0; ms < 4; ++ms)
      #pragma unroll
      for (int r = 0; r < 4; ++r)
        atomicAdd(&lp[ms * 16 + quad * 4 + r], accl[ms * 4 + r]);
  }
}

// ---------------- K3: pass B  w[t] = sum_s exp(q_s.k_t/16) / l[s] ----------
// Mirror: A = 64 k-rows/wave; queries streamed; 1/l from LDS copy.
__global__ __launch_bounds__(256, 3) void scores_w_kernel(
    const uint8_t* __restrict__ q8, const uint8_t* __restrict__ k8,
    const float* __restrict__ lacc, float* __restrict__ wacc) {
  __shared__ char qt[2][16384];
  __shared__ float rls[256];
  const int tid = threadIdx.x;
  const int lane = tid & 63, wave = tid >> 6, quad = lane >> 4, lr = lane & 15;
  const int idx = blockIdx.x;
  const int b = idx >> 8, rem = idx & 255, kblk = rem >> 4, sch = rem & 15;
  const uint8_t* kb = k8 + (size_t)(b * SS + kblk * 256 + wave * 64) * EE;
  const uint8_t* qw = q8 + (size_t)(b * SS + sch * 256) * EE;
  rls[tid] = lacc[b * SS + sch * 256 + tid];
  stage_fp8_64(qw, qt[0], tid);
  i32x8 a[4][2];
  #pragma unroll
  for (int ms = 0; ms < 4; ++ms)
    #pragma unroll
    for (int win = 0; win < 2; ++win)
      a[ms][win] = *(const i32x8*)(kb + (size_t)(ms * 16 + lr) * EE + win * 128 + quad * 32);
  float accw[16];
  #pragma unroll
  for (int i = 0; i < 16; ++i) accw[i] = 0.f;
  for (int it = 0; it < 4; ++it) {
    __syncthreads();
    if (it + 1 < 4) stage_fp8_64(qw + (size_t)(it + 1) * 64 * EE, qt[(it + 1) & 1], tid);
    const char* tile = qt[it & 1];
    #pragma unroll
    for (int nt = 0; nt < 4; ++nt) {
      float rlv = RCP(rls[it * 64 + nt * 16 + lr]);   // 1/l for col s
      i32x8 bf0 = read_frag8(tile, nt * 16 + lr, 0, quad);
      i32x8 bf1 = read_frag8(tile, nt * 16 + lr, 1, quad);
      f32x4 acc[4] = {};
      #pragma unroll
      for (int ms = 0; ms < 4; ++ms) {
        acc[ms] = mfma128(a[ms][0], bf0, acc[ms]);
        acc[ms] = mfma128(a[ms][1], bf1, acc[ms]);
      }
      #pragma unroll
      for (int ms = 0; ms < 4; ++ms)
        #pragma unroll
        for (int r = 0; r < 4; ++r)
          accw[ms * 4 + r] += EXP2(acc[ms][r] * C2) * rlv;
    }
  }
  #pragma unroll
  for (int d = 1; d < 16; d <<= 1)
    #pragma unroll
    for (int i = 0; i < 16; ++i)
      accw[i] += __shfl_xor(accw[i], d, 64);
  if (lr == 0) {
    float* wp = wacc + b * SS + kblk * 256 + wave * 64;
    #pragma unroll
    for (int ms = 0; ms < 4; ++ms)
      #pragma unroll
      for (int r = 0; r < 4; ++r)
        atomicAdd(&wp[ms * 16 + quad * 4 + r], accw[ms * 4 + r]);
  }
}

// ---------------- K4: pool — out[b,e] += (1/S) sum_t w[t] v[t,e] ------------
__global__ void pool_kernel(const float* __restrict__ wsum, const uint16_t* __restrict__ v,
                            float* __restrict__ out) {
  __shared__ float red[4][256];
  const int b = blockIdx.x >> 6, tc = blockIdx.x & 63;
  const int tq = threadIdx.x >> 6, eg = threadIdx.x & 63;
  float acc[4] = {0.f, 0.f, 0.f, 0.f};
  const float* wp = wsum + b * SS + tc * 64;
  const uint16_t* vp = v + (size_t)(b * SS + tc * 64) * EE + eg * 4;
  #pragma unroll
  for (int t = 0; t < 16; ++t) {
    int row = t * 4 + tq;
    float wv = wp[row];
    ushort4 x4 = *(const ushort4*)(vp + (size_t)row * EE);
    acc[0] += wv * bf2f(x4.x);
    acc[1] += wv * bf2f(x4.y);
    acc[2] += wv * bf2f(x4.z);
    acc[3] += wv * bf2f(x4.w);
  }
  #pragma unroll
  for (int j = 0; j < 4; ++j) red[tq][eg * 4 + j] = acc[j];
  __syncthreads();
  if (tq == 0) {
    const float inv = 1.0f / 4096.0f;
    #pragma unroll
    for (int j = 0; j < 4; ++j) {
      float s = red[0][eg * 4 + j] + red[1][eg * 4 + j] +
                red[2][eg * 4 + j] + red[3][eg * 4 + j];
      atomicAdd(&out[b * 256 + eg * 4 + j], s * inv);
    }
  }
}

// ---------------- launch ----------------
extern "C" void kernel_launch(void* const* d_in, const int* in_sizes, int n_in,
                              void* d_out, int out_size, void* d_ws, size_t ws_size,
                              hipStream_t stream) {
  const float* x  = (const float*)d_in[0];
  const float* Wq = (const float*)d_in[1];
  const float* bq = (const float*)d_in[2];
  const float* Wk = (const float*)d_in[3];
  const float* bk = (const float*)d_in[4];
  const float* Wv = (const float*)d_in[5];
  const float* bv = (const float*)d_in[6];

  char* ws = (char*)d_ws;
  uint8_t*  q8   = (uint8_t*)(ws);               //  4 MB  q fp8
  uint8_t*  k8   = (uint8_t*)(ws + 4194304);     //  4 MB  k fp8
  uint16_t* vb   = (uint16_t*)(ws + 8388608);    //  8 MB  v bf16
  uint16_t* wt   = (uint16_t*)(ws + 16777216);   // 384 KB WT bf16
  float* l_arr   = (float*)(ws + 17170432);      // 64 KB  row sums
  float* w_arr   = (float*)(ws + 17235968);      // 64 KB  col weights (contiguous)
  float* out     = (float*)d_out;

  prep_kernel<<<81, 256, 0, stream>>>(Wq, Wk, Wv, wt, l_arr, out);
  qkv_kernel<<<512, 256, 0, stream>>>(x, wt, bq, bk, bv, q8, k8, vb);
  scores_l_kernel<<<1024, 256, 0, stream>>>(q8, k8, l_arr);
  scores_w_kernel<<<1024, 256, 0, stream>>>(q8, k8, l_arr, w_arr);
  pool_kernel<<<256, 256, 0, stream>>>(w_arr, vb, out);
}